// Round 8
// baseline (185.925 us; speedup 1.0000x reference)
//
#include <hip/hip_runtime.h>
#include <math.h>

#define BB 8
#define HH 16
#define NN 1024
#define TB 256
#define NSC 4            // scan chunks per bh
#define SCH 256          // scan points per chunk (NN / NSC)
#define POWN 4           // own points per thread (block owns all 1024)
#define SUMBASE (BB * HH * NSC * NN)   // 512K floats of partials, then sums

// ws layout (floats):
//   [0, SUMBASE)             part[(bh*NSC+sc)*NN + i] (2 MB, coalesced)
//   [SUMBASE, SUMBASE+128)   per-bh sums
// Every used slot written every iteration, no reads of unwritten ws.

// Self-resetting ticket counters (zero-initialized at module load; the
// claiming block resets them to 0 for the next iteration, so no init
// dispatch is needed and graph replay is safe).
__device__ int g_cnt_bh[BB * HH];
__device__ int g_cnt_b[BB];

// ---------------------------------------------------------------------------
// ROUND-8: single fused kernel (rocPRIM-style last-block tickets).
// Rounds 5-7 established: chamfer is at its ~6-7 us VALU floor, the merged
// 8-block reduce regresses (r6), and the remaining controllable cost is the
// 3-dispatch structure itself (2 extra launches + 2 small-kernel latency
// floors). Here:
//   phase 1 (all 512 blocks): r5's chamfer verbatim (POWN=4, SCH=256,
//     256 broadcast ds_read_b128/wave) -> 2 MB partials.
//   phase 2 (last block per bh, 128 blocks total -- same parallelism as
//     r5's separate reduce): threadfence-acquire, r5's coalesced 4-row
//     float4 reduce, write sums[bh].
//   phase 3 (last block per batch, 8 blocks): r7's finalize verbatim.
// No spinning: non-last blocks exit. Device-scope fences around each
// ticket handle cross-XCD L2 visibility (G16). All expression trees
// bit-identical to the passing r5/r7 kernels.
// ---------------------------------------------------------------------------
__global__ __launch_bounds__(TB) void fused_kernel(
    const float* __restrict__ y_pred,
    const float* __restrict__ sp,
    float* __restrict__ ws,
    float* __restrict__ out)
{
    __shared__ __align__(16) float4 pts[SCH];   // 4 KB
    __shared__ float wsum[4];
    __shared__ int s_last;
    __shared__ float sde_s[HH], nx_s[HH], ny_s[HH], nz_s[HH], d_s[HH], conf_s[HH];
    __shared__ float cmacc[3];
    __shared__ int keep_s[HH];

    const int blk = blockIdx.x;          // 512 blocks
    const int bh  = blk >> 2;
    const int sc  = blk & (NSC - 1);
    const int b   = bh >> 4;             // HH = 16
    const int tid = threadIdx.x;

    // ======================= phase 1: chamfer (r5) =======================
    {
        float pnx = y_pred[bh * 4 + 0];
        float pny = y_pred[bh * 4 + 1];
        float pnz = y_pred[bh * 4 + 2];
        float pd  = y_pred[bh * 4 + 3];
        float inv = 1.0f / sqrtf(pnx * pnx + pny * pny + pnz * pnz);
        pnx *= inv; pny *= inv; pnz *= inv;

        const float* __restrict__ spb = sp + (size_t)b * NN * 3;

        // stage scan chunk: raw samples with squared norm (1 point / thread)
        {
            int j = sc * SCH + tid;
            float x = spb[j * 3 + 0], y = spb[j * 3 + 1], z = spb[j * 3 + 2];
            pts[tid] = make_float4(x, y, z, x * x + y * y + z * z);
        }

        // own points: reflected, pre-scaled by -2
        float mx[POWN], my[POWN], mz[POWN], osq[POWN];
#pragma unroll
        for (int u = 0; u < POWN; ++u) {
            int i = u * TB + tid;
            float x = spb[i * 3 + 0], y = spb[i * 3 + 1], z = spb[i * 3 + 2];
            float proj = x * pnx + y * pny + z * pnz + pd;
            x -= 2.0f * proj * pnx;
            y -= 2.0f * proj * pny;
            z -= 2.0f * proj * pnz;
            osq[u] = x * x + y * y + z * z;
            mx[u] = -2.0f * x; my[u] = -2.0f * y; mz[u] = -2.0f * z;
        }
        __syncthreads();

        float m0[POWN], m1[POWN];
#pragma unroll
        for (int u = 0; u < POWN; ++u) { m0[u] = 3.4e38f; m1[u] = 3.4e38f; }

#define DIST(qq, u) fmaf(mx[u], qq.x, fmaf(my[u], qq.y, fmaf(mz[u], qq.z, qq.w)))
        for (int j = 0; j < SCH; j += 4) {
            float4 q0 = pts[j + 0];
            float4 q1 = pts[j + 1];
            float4 q2 = pts[j + 2];
            float4 q3 = pts[j + 3];
#pragma unroll
            for (int u = 0; u < POWN; ++u) {
                float d0 = DIST(q0, u);
                float d1 = DIST(q1, u);
                float d2 = DIST(q2, u);
                float d3 = DIST(q3, u);
                m0[u] = fminf(fminf(m0[u], d0), d1);   // v_min3_f32
                m1[u] = fminf(fminf(m1[u], d2), d3);
            }
        }
#undef DIST

        float* wp = ws + (size_t)(bh * NSC + sc) * NN;
#pragma unroll
        for (int u = 0; u < POWN; ++u)
            wp[u * TB + tid] = osq[u] + fminf(m0[u], m1[u]);
    }

    // ---- ticket: last block of this bh does the reduce ----
    __threadfence();                     // release partials device-wide
    __syncthreads();
    if (tid == 0) {
        int t = atomicAdd(&g_cnt_bh[bh], 1);
        s_last = (t == NSC - 1) ? 1 : 0;
    }
    __syncthreads();
    if (!s_last) return;

    // ======================= phase 2: reduce (r5) ========================
    __threadfence();                     // acquire other blocks' partials
    {
        const float* base = ws + (size_t)(bh * NSC) * NN;
        const float4* r0 = (const float4*)(base + 0 * NN);
        const float4* r1 = (const float4*)(base + 1 * NN);
        const float4* r2 = (const float4*)(base + 2 * NN);
        const float4* r3 = (const float4*)(base + 3 * NN);

        float4 a0 = r0[tid], a1 = r1[tid], a2 = r2[tid], a3 = r3[tid];
        float e0 = fminf(fminf(a0.x, a1.x), fminf(a2.x, a3.x));
        float e1 = fminf(fminf(a0.y, a1.y), fminf(a2.y, a3.y));
        float e2 = fminf(fminf(a0.z, a1.z), fminf(a2.z, a3.z));
        float e3 = fminf(fminf(a0.w, a1.w), fminf(a2.w, a3.w));
        float s  = (e0 + e1) + (e2 + e3);

        for (int off = 32; off; off >>= 1) s += __shfl_down(s, off, 64);
        if ((tid & 63) == 0) wsum[tid >> 6] = s;
        __syncthreads();
        if (tid == 0)
            ws[SUMBASE + bh] = (wsum[0] + wsum[1]) + (wsum[2] + wsum[3]);
    }

    // ---- ticket: last bh of this batch does the finalize ----
    __threadfence();                     // release sums[bh]
    __syncthreads();
    if (tid == 0) {
        atomicExch(&g_cnt_bh[bh], 0);    // reset for next iteration
        int t = atomicAdd(&g_cnt_b[b], 1);
        s_last = (t == HH - 1) ? 1 : 0;
    }
    __syncthreads();
    if (!s_last) return;

    // ======================= phase 3: finalize (r7) ======================
    __threadfence();                     // acquire all sums of this batch
    if (tid == 0) atomicExch(&g_cnt_b[b], 0);   // reset for next iteration

    if (tid < 3) cmacc[tid] = 0.0f;
    __syncthreads();

    // centroid: 1024 samples over 256 threads
    const float* spb = sp + (size_t)b * NN * 3;
    {
        float sx = 0.0f, sy = 0.0f, sz = 0.0f;
        for (int p = tid; p < NN; p += TB) {
            sx += spb[p * 3 + 0];
            sy += spb[p * 3 + 1];
            sz += spb[p * 3 + 2];
        }
        for (int off = 32; off; off >>= 1) {
            sx += __shfl_down(sx, off, 64);
            sy += __shfl_down(sy, off, 64);
            sz += __shfl_down(sz, off, 64);
        }
        if ((tid & 63) == 0) {
            atomicAdd(&cmacc[0], sx);
            atomicAdd(&cmacc[1], sy);
            atomicAdd(&cmacc[2], sz);
        }
    }
    __syncthreads();

    const float cmx = cmacc[0] / NN, cmy = cmacc[1] / NN, cmz = cmacc[2] / NN;

    if (tid < HH) {
        int h = tid;
        float nx = y_pred[(b * HH + h) * 4 + 0];
        float ny = y_pred[(b * HH + h) * 4 + 1];
        float nz = y_pred[(b * HH + h) * 4 + 2];
        float d  = y_pred[(b * HH + h) * 4 + 3];
        float inv = 1.0f / sqrtf(nx * nx + ny * ny + nz * nz);
        nx *= inv; ny *= inv; nz *= inv;
        nx_s[h] = nx; ny_s[h] = ny; nz_s[h] = nz; d_s[h] = d;
        // both chamfer terms equal -> 2/N * per-bh sum
        sde_s[h] = ws[SUMBASE + b * HH + h] * (2.0f / NN);
    }
    __syncthreads();

    if (tid < HH) {
        int h = tid;
        float mn = sde_s[0], mx = sde_s[0];
        for (int g = 1; g < HH; ++g) {
            mn = fminf(mn, sde_s[g]);
            mx = fmaxf(mx, sde_s[g]);
        }
        float sde  = sde_s[h];
        float conf = 1.0f - (sde - mn) / fabsf(mx - mn);
        conf_s[h]  = conf;
        bool valid = (sde <= 10.0f);
        bool sup   = false;
        if (valid) {
            for (int g = 0; g < HH; ++g) {
                if (g == h) continue;
                float c = nx_s[h] * nx_s[g] + ny_s[h] * ny_s[g] + nz_s[h] * nz_s[g];
                c = fminf(1.0f, fmaxf(-1.0f, c));
                float ang = acosf(c) * 57.29577951308232f;
                bool close = (ang < 30.0f) || (180.0f - ang < 30.0f);
                if (close && (sde_s[g] <= 10.0f) && (sde >= sde_s[g])) sup = true;
            }
        }
        keep_s[h] = (valid && !sup) ? 1 : 0;
    }
    __syncthreads();

    if (tid < HH) {
        int h = tid;
        // stable descending rank on key = keep ? conf : -inf (jnp.argsort(-key))
        float keyh = keep_s[h] ? conf_s[h] : -INFINITY;
        int pos = 0;
        for (int g = 0; g < HH; ++g) {
            float keyg = keep_s[g] ? conf_s[g] : -INFINITY;
            if (keyg > keyh || (keyg == keyh && g < h)) ++pos;
        }
        float nx = nx_s[h], ny = ny_s[h], nz = nz_s[h];
        float t  = nx * cmx + ny * cmy + nz * cmz + d_s[h];
        float px = cmx - t * nx, py = cmy - t * ny, pz = cmz - t * nz;

        float* o = out + (size_t)(b * HH + pos) * 8;
        if (keep_s[h]) {
            o[0] = nx; o[1] = ny; o[2] = nz;
            o[3] = px; o[4] = py; o[5] = pz;
            o[6] = conf_s[h];
            o[7] = sde_s[h];
        } else {
            for (int c = 0; c < 8; ++c) o[c] = 0.0f;
        }
    }
}

extern "C" void kernel_launch(void* const* d_in, const int* in_sizes, int n_in,
                              void* d_out, int out_size, void* d_ws, size_t ws_size,
                              hipStream_t stream) {
    const float* y_pred = (const float*)d_in[0];   // (8,16,4) f32
    const float* sp     = (const float*)d_in[1];   // (8,1024,3) f32
    float* out          = (float*)d_out;           // (8,16,8) f32
    float* ws           = (float*)d_ws;            // 2 MB partials + 128 sums

    fused_kernel<<<dim3(BB * HH * NSC), dim3(TB), 0, stream>>>(y_pred, sp, ws, out);
}

// Round 9
// 73.522 us; speedup vs baseline: 2.5288x; 2.5288x over previous
//
#include <hip/hip_runtime.h>
#include <math.h>

#define BB 8
#define HH 16
#define NN 1024
#define TB 256
#define SCH 256          // scan chunk per wave == own points per block

// ws layout (floats): ws[bh*4 + q] = sum over own-quarter q's 256 points of
// full min_j d2(reflected_i, sp_j). 512 floats, written once per iteration,
// plain stores, no atomics, no fences, no init.

// ---------------------------------------------------------------------------
// chamfer: ONLY pass A (reflection-isometry: both chamfer terms equal).
// ROUND-9: complete min_j IN-BLOCK without fences (r8's threadfence-ticket
// fusion cost ~0.3 us of serialized L2 writeback PER BLOCK -- 161 us; dead
// end). Block (bh, q): stages ALL 1024 points in LDS (16 KB); own = points
// [q*256, +256), 4 per lane (i_local = lane + 64u); WAVE w scans only chunk
// w (256 broadcast ds_read_b128/wave -- identical LDS-pipe load and VALU
// count to the r5 champion). Each wave covers all 256 own points, so the
// 4 per-chunk partial mins meet in a conflict-free part[4][256] LDS array;
// thread t mins them in fixed order, adds its osq, and the block lane-tree
// sums to ONE float. Numerically: osq + min_w(cm_w) == min_w(osq + cm_w)
// bitwise (same operands reach the final fadd), so values equal r5's; the
// i-sum order is r2's exact passing order.
// ---------------------------------------------------------------------------
__global__ __launch_bounds__(TB) void chamfer_kernel(
    const float* __restrict__ y_pred,
    const float* __restrict__ sp,
    float* __restrict__ ws)
{
    __shared__ __align__(16) float4 pts[NN];    // 16 KB
    __shared__ float part[4][SCH];              // 4 KB, [wave][i_local]
    __shared__ float wsum[4];

    const int blk = blockIdx.x;          // 512 blocks
    const int bh  = blk >> 2;
    const int q   = blk & 3;
    const int b   = bh >> 4;             // HH = 16
    const int tid = threadIdx.x;
    const int w   = tid >> 6;            // wave 0..3
    const int l   = tid & 63;            // lane

    float pnx = y_pred[bh * 4 + 0];
    float pny = y_pred[bh * 4 + 1];
    float pnz = y_pred[bh * 4 + 2];
    float pd  = y_pred[bh * 4 + 3];
    float inv = 1.0f / sqrtf(pnx * pnx + pny * pny + pnz * pnz);
    pnx *= inv; pny *= inv; pnz *= inv;

    const float* __restrict__ spb = sp + (size_t)b * NN * 3;

    // stage ALL scan points with squared norm (4 per thread)
    for (int k = tid; k < NN; k += TB) {
        float x = spb[k * 3 + 0], y = spb[k * 3 + 1], z = spb[k * 3 + 2];
        pts[k] = make_float4(x, y, z, x * x + y * y + z * z);
    }
    __syncthreads();

    // own points (4/lane, i_local = l + 64u): reflected, pre-scaled by -2.
    // xyz read back from LDS (bit-identical to the global values staged).
    float mx[4], my[4], mz[4], osq[4];
#pragma unroll
    for (int u = 0; u < 4; ++u) {
        float4 P = pts[q * SCH + l + 64 * u];
        float x = P.x, y = P.y, z = P.z;
        float proj = x * pnx + y * pny + z * pnz + pd;
        x -= 2.0f * proj * pnx;
        y -= 2.0f * proj * pny;
        z -= 2.0f * proj * pnz;
        osq[u] = x * x + y * y + z * z;
        mx[u] = -2.0f * x; my[u] = -2.0f * y; mz[u] = -2.0f * z;
    }

    float m0[4], m1[4];
#pragma unroll
    for (int u = 0; u < 4; ++u) { m0[u] = 3.4e38f; m1[u] = 3.4e38f; }

    // wave w scans chunk w: 256 broadcast ds_read_b128 per wave
    const float4* __restrict__ chunk = pts + w * SCH;

#define DIST(qq, u) fmaf(mx[u], qq.x, fmaf(my[u], qq.y, fmaf(mz[u], qq.z, qq.w)))
    for (int j = 0; j < SCH; j += 4) {
        float4 q0 = chunk[j + 0];
        float4 q1 = chunk[j + 1];
        float4 q2 = chunk[j + 2];
        float4 q3 = chunk[j + 3];
#pragma unroll
        for (int u = 0; u < 4; ++u) {
            float d0 = DIST(q0, u);
            float d1 = DIST(q1, u);
            float d2 = DIST(q2, u);
            float d3 = DIST(q3, u);
            m0[u] = fminf(fminf(m0[u], d0), d1);   // v_min3_f32
            m1[u] = fminf(fminf(m1[u], d2), d3);
        }
    }
#undef DIST

    // cross-wave combine: part[w][i_local], conflict-free (lanes stride 1)
#pragma unroll
    for (int u = 0; u < 4; ++u)
        part[w][l + 64 * u] = fminf(m0[u], m1[u]);
    __syncthreads();

    float p0 = part[0][tid], p1 = part[1][tid];
    float p2 = part[2][tid], p3 = part[3][tid];
    float cmin = fminf(fminf(p0, p1), fminf(p2, p3));
    // thread t's own point is i_local = t = l + 64*w  ->  its osq is osq[w];
    // static-select to keep osq[] in registers (rule #20)
    float osq_own = (w == 0) ? osq[0] : (w == 1) ? osq[1]
                  : (w == 2) ? osq[2] : osq[3];
    float dmin = osq_own + cmin;           // complete min_j d2 for own i

    // in-block sum over 256 own points (r2's exact passing order)
    float s = dmin;
    for (int off = 32; off; off >>= 1) s += __shfl_down(s, off, 64);
    if (l == 0) wsum[w] = s;
    __syncthreads();
    if (tid == 0)
        ws[bh * 4 + q] = (wsum[0] + wsum[1]) + (wsum[2] + wsum[3]);
}

// ---------------------------------------------------------------------------
// finalize (per batch, 256 threads): centroid; sde[h] = 2/N * (4 block sums
// in fixed order); conf; angle-NMS; stable rank; write. Verbatim round 2
// (which passed with absmax 0).
// ---------------------------------------------------------------------------
__global__ __launch_bounds__(TB) void finalize_kernel(
    const float* __restrict__ ws,
    const float* __restrict__ y_pred,
    const float* __restrict__ sp,
    float* __restrict__ out)
{
    const int b   = blockIdx.x;
    const int tid = threadIdx.x;

    __shared__ float sde_s[HH], nx_s[HH], ny_s[HH], nz_s[HH], d_s[HH], conf_s[HH];
    __shared__ float cmacc[3];
    __shared__ int keep_s[HH];

    if (tid < 3) cmacc[tid] = 0.0f;
    __syncthreads();

    // centroid: 1024 samples over 256 threads
    const float* spb = sp + (size_t)b * NN * 3;
    float sx = 0.0f, sy = 0.0f, sz = 0.0f;
    for (int p = tid; p < NN; p += TB) {
        sx += spb[p * 3 + 0];
        sy += spb[p * 3 + 1];
        sz += spb[p * 3 + 2];
    }
    for (int off = 32; off; off >>= 1) {
        sx += __shfl_down(sx, off, 64);
        sy += __shfl_down(sy, off, 64);
        sz += __shfl_down(sz, off, 64);
    }
    if ((tid & 63) == 0) {
        atomicAdd(&cmacc[0], sx);
        atomicAdd(&cmacc[1], sy);
        atomicAdd(&cmacc[2], sz);
    }
    __syncthreads();

    const float cmx = cmacc[0] / NN, cmy = cmacc[1] / NN, cmz = cmacc[2] / NN;

    if (tid < HH) {
        int h = tid;
        float nx = y_pred[(b * HH + h) * 4 + 0];
        float ny = y_pred[(b * HH + h) * 4 + 1];
        float nz = y_pred[(b * HH + h) * 4 + 2];
        float d  = y_pred[(b * HH + h) * 4 + 3];
        float inv = 1.0f / sqrtf(nx * nx + ny * ny + nz * nz);
        nx *= inv; ny *= inv; nz *= inv;
        nx_s[h] = nx; ny_s[h] = ny; nz_s[h] = nz; d_s[h] = d;
        const float* w = ws + (size_t)(b * HH + h) * 4;
        // fixed-order sum of the 4 block partials, both chamfer terms equal
        sde_s[h] = ((w[0] + w[1]) + (w[2] + w[3])) * (2.0f / NN);
    }
    __syncthreads();

    if (tid < HH) {
        int h = tid;
        float mn = sde_s[0], mx = sde_s[0];
        for (int g = 1; g < HH; ++g) {
            mn = fminf(mn, sde_s[g]);
            mx = fmaxf(mx, sde_s[g]);
        }
        float sde  = sde_s[h];
        float conf = 1.0f - (sde - mn) / fabsf(mx - mn);
        conf_s[h]  = conf;
        bool valid = (sde <= 10.0f);
        bool sup   = false;
        if (valid) {
            for (int g = 0; g < HH; ++g) {
                if (g == h) continue;
                float c = nx_s[h] * nx_s[g] + ny_s[h] * ny_s[g] + nz_s[h] * nz_s[g];
                c = fminf(1.0f, fmaxf(-1.0f, c));
                float ang = acosf(c) * 57.29577951308232f;
                bool close = (ang < 30.0f) || (180.0f - ang < 30.0f);
                if (close && (sde_s[g] <= 10.0f) && (sde >= sde_s[g])) sup = true;
            }
        }
        keep_s[h] = (valid && !sup) ? 1 : 0;
    }
    __syncthreads();

    if (tid < HH) {
        int h = tid;
        // stable descending rank on key = keep ? conf : -inf (jnp.argsort(-key))
        float keyh = keep_s[h] ? conf_s[h] : -INFINITY;
        int pos = 0;
        for (int g = 0; g < HH; ++g) {
            float keyg = keep_s[g] ? conf_s[g] : -INFINITY;
            if (keyg > keyh || (keyg == keyh && g < h)) ++pos;
        }
        float nx = nx_s[h], ny = ny_s[h], nz = nz_s[h];
        float t  = nx * cmx + ny * cmy + nz * cmz + d_s[h];
        float px = cmx - t * nx, py = cmy - t * ny, pz = cmz - t * nz;

        float* o = out + (size_t)(b * HH + pos) * 8;
        if (keep_s[h]) {
            o[0] = nx; o[1] = ny; o[2] = nz;
            o[3] = px; o[4] = py; o[5] = pz;
            o[6] = conf_s[h];
            o[7] = sde_s[h];
        } else {
            for (int c = 0; c < 8; ++c) o[c] = 0.0f;
        }
    }
}

extern "C" void kernel_launch(void* const* d_in, const int* in_sizes, int n_in,
                              void* d_out, int out_size, void* d_ws, size_t ws_size,
                              hipStream_t stream) {
    const float* y_pred = (const float*)d_in[0];   // (8,16,4) f32
    const float* sp     = (const float*)d_in[1];   // (8,1024,3) f32
    float* out          = (float*)d_out;           // (8,16,8) f32
    float* ws           = (float*)d_ws;            // 512 floats of block sums

    chamfer_kernel<<<dim3(BB * HH * 4), dim3(TB), 0, stream>>>(y_pred, sp, ws);
    finalize_kernel<<<dim3(BB), dim3(TB), 0, stream>>>(ws, y_pred, sp, out);
}

// Round 10
// 73.474 us; speedup vs baseline: 2.5305x; 1.0007x over previous
//
#include <hip/hip_runtime.h>
#include <math.h>

#define BB 8
#define HH 16
#define NN 1024
#define TBC 512          // chamfer block: 8 waves
#define OWN 512          // own points per block (half of NN)
#define CHK 128          // scan chunk per wave (NN / 8 waves)
#define TB 256           // finalize block

// ws layout (floats): ws[bh*2 + half] = sum over own-half's 512 points of
// full min_j d2(reflected_i, sp_j). 256 floats, written once per iteration,
// plain stores, no atomics, no fences, no init.

// ---------------------------------------------------------------------------
// chamfer: ONLY pass A (reflection-isometry: both chamfer terms equal).
// ROUND-10: r9's in-block-complete structure with the broadcast stream
// halved. r9: 4 waves x 256 reads/wave -> per-CU LDS ~7.7 us, marginally
// above the ~6 us VALU floor. Here: block (bh, half) = 8 waves (TBC=512);
// own = 512 points (8/lane, i_local = l + 64u); wave w scans only chunk w
// (128 broadcast ds_read_b128/wave) -> per-CU LDS ~3.8 us, safely under
// the VALU floor. Grid = 256 blocks (1/CU, 8 waves/CU -- same occupancy).
// r7's null A/B on POWN=8 is explained: its reduce kernel simultaneously
// doubled (4 MB); no reduce dispatch exists here to mask the result.
// Cross-wave combine via conflict-free part[8][512]; min over 8 chunk
// partials = same value set as r9 (min order-insensitive, no NaNs);
// block lane-tree sum -> ONE float. No fences (r8 lesson), no register
// rotation (r1), no SMEM (r3/r4).
// ---------------------------------------------------------------------------
__global__ __launch_bounds__(TBC) void chamfer_kernel(
    const float* __restrict__ y_pred,
    const float* __restrict__ sp,
    float* __restrict__ ws)
{
    __shared__ __align__(16) float4 pts[NN];    // 16 KB
    __shared__ float part[8][OWN];              // 16 KB, [wave][i_local]
    __shared__ float wsum[8];

    const int blk  = blockIdx.x;         // 256 blocks
    const int bh   = blk >> 1;
    const int half = blk & 1;
    const int b    = bh >> 4;            // HH = 16
    const int tid  = threadIdx.x;
    const int w    = tid >> 6;           // wave 0..7
    const int l    = tid & 63;           // lane

    float pnx = y_pred[bh * 4 + 0];
    float pny = y_pred[bh * 4 + 1];
    float pnz = y_pred[bh * 4 + 2];
    float pd  = y_pred[bh * 4 + 3];
    float inv = 1.0f / sqrtf(pnx * pnx + pny * pny + pnz * pnz);
    pnx *= inv; pny *= inv; pnz *= inv;

    const float* __restrict__ spb = sp + (size_t)b * NN * 3;

    // stage ALL scan points with squared norm (2 per thread)
    for (int k = tid; k < NN; k += TBC) {
        float x = spb[k * 3 + 0], y = spb[k * 3 + 1], z = spb[k * 3 + 2];
        pts[k] = make_float4(x, y, z, x * x + y * y + z * z);
    }
    __syncthreads();

    // own points (8/lane, i_local = l + 64u): reflected, pre-scaled by -2.
    float mx[8], my[8], mz[8], osq[8];
#pragma unroll
    for (int u = 0; u < 8; ++u) {
        float4 P = pts[half * OWN + l + 64 * u];
        float x = P.x, y = P.y, z = P.z;
        float proj = x * pnx + y * pny + z * pnz + pd;
        x -= 2.0f * proj * pnx;
        y -= 2.0f * proj * pny;
        z -= 2.0f * proj * pnz;
        osq[u] = x * x + y * y + z * z;
        mx[u] = -2.0f * x; my[u] = -2.0f * y; mz[u] = -2.0f * z;
    }

    float m0[8], m1[8];
#pragma unroll
    for (int u = 0; u < 8; ++u) { m0[u] = 3.4e38f; m1[u] = 3.4e38f; }

    // wave w scans chunk w: 128 broadcast ds_read_b128 per wave
    const float4* __restrict__ chunk = pts + w * CHK;

#define DIST(qq, u) fmaf(mx[u], qq.x, fmaf(my[u], qq.y, fmaf(mz[u], qq.z, qq.w)))
    for (int j = 0; j < CHK; j += 4) {
        float4 q0 = chunk[j + 0];
        float4 q1 = chunk[j + 1];
        float4 q2 = chunk[j + 2];
        float4 q3 = chunk[j + 3];
#pragma unroll
        for (int u = 0; u < 8; ++u) {
            float d0 = DIST(q0, u);
            float d1 = DIST(q1, u);
            float d2 = DIST(q2, u);
            float d3 = DIST(q3, u);
            m0[u] = fminf(fminf(m0[u], d0), d1);   // v_min3_f32
            m1[u] = fminf(fminf(m1[u], d2), d3);
        }
    }
#undef DIST

    // cross-wave combine: part[w][i_local], conflict-free (lanes stride 1)
#pragma unroll
    for (int u = 0; u < 8; ++u)
        part[w][l + 64 * u] = fminf(m0[u], m1[u]);
    __syncthreads();

    float p0 = part[0][tid], p1 = part[1][tid];
    float p2 = part[2][tid], p3 = part[3][tid];
    float p4 = part[4][tid], p5 = part[5][tid];
    float p6 = part[6][tid], p7 = part[7][tid];
    float cmin = fminf(fminf(fminf(p0, p1), fminf(p2, p3)),
                       fminf(fminf(p4, p5), fminf(p6, p7)));
    // thread t's own point is i_local = t = l + 64*w -> its osq is osq[w];
    // static-select to keep osq[] in registers (rule #20)
    float osq_own = (w == 0) ? osq[0] : (w == 1) ? osq[1]
                  : (w == 2) ? osq[2] : (w == 3) ? osq[3]
                  : (w == 4) ? osq[4] : (w == 5) ? osq[5]
                  : (w == 6) ? osq[6] : osq[7];
    float dmin = osq_own + cmin;           // complete min_j d2 for own i

    // in-block sum over 512 own points (lane tree + fixed-order 8-wave combine)
    float s = dmin;
    for (int off = 32; off; off >>= 1) s += __shfl_down(s, off, 64);
    if (l == 0) wsum[w] = s;
    __syncthreads();
    if (tid == 0)
        ws[bh * 2 + half] = ((wsum[0] + wsum[1]) + (wsum[2] + wsum[3]))
                          + ((wsum[4] + wsum[5]) + (wsum[6] + wsum[7]));
}

// ---------------------------------------------------------------------------
// finalize (per batch, 256 threads): centroid; sde[h] = 2/N * (2 block sums
// in fixed order); conf; angle-NMS; stable rank; write. Verbatim r9 except
// the 2-partial sum.
// ---------------------------------------------------------------------------
__global__ __launch_bounds__(TB) void finalize_kernel(
    const float* __restrict__ ws,
    const float* __restrict__ y_pred,
    const float* __restrict__ sp,
    float* __restrict__ out)
{
    const int b   = blockIdx.x;
    const int tid = threadIdx.x;

    __shared__ float sde_s[HH], nx_s[HH], ny_s[HH], nz_s[HH], d_s[HH], conf_s[HH];
    __shared__ float cmacc[3];
    __shared__ int keep_s[HH];

    if (tid < 3) cmacc[tid] = 0.0f;
    __syncthreads();

    // centroid: 1024 samples over 256 threads
    const float* spb = sp + (size_t)b * NN * 3;
    float sx = 0.0f, sy = 0.0f, sz = 0.0f;
    for (int p = tid; p < NN; p += TB) {
        sx += spb[p * 3 + 0];
        sy += spb[p * 3 + 1];
        sz += spb[p * 3 + 2];
    }
    for (int off = 32; off; off >>= 1) {
        sx += __shfl_down(sx, off, 64);
        sy += __shfl_down(sy, off, 64);
        sz += __shfl_down(sz, off, 64);
    }
    if ((tid & 63) == 0) {
        atomicAdd(&cmacc[0], sx);
        atomicAdd(&cmacc[1], sy);
        atomicAdd(&cmacc[2], sz);
    }
    __syncthreads();

    const float cmx = cmacc[0] / NN, cmy = cmacc[1] / NN, cmz = cmacc[2] / NN;

    if (tid < HH) {
        int h = tid;
        float nx = y_pred[(b * HH + h) * 4 + 0];
        float ny = y_pred[(b * HH + h) * 4 + 1];
        float nz = y_pred[(b * HH + h) * 4 + 2];
        float d  = y_pred[(b * HH + h) * 4 + 3];
        float inv = 1.0f / sqrtf(nx * nx + ny * ny + nz * nz);
        nx *= inv; ny *= inv; nz *= inv;
        nx_s[h] = nx; ny_s[h] = ny; nz_s[h] = nz; d_s[h] = d;
        const float* w = ws + (size_t)(b * HH + h) * 2;
        // fixed-order sum of the 2 block partials, both chamfer terms equal
        sde_s[h] = (w[0] + w[1]) * (2.0f / NN);
    }
    __syncthreads();

    if (tid < HH) {
        int h = tid;
        float mn = sde_s[0], mx = sde_s[0];
        for (int g = 1; g < HH; ++g) {
            mn = fminf(mn, sde_s[g]);
            mx = fmaxf(mx, sde_s[g]);
        }
        float sde  = sde_s[h];
        float conf = 1.0f - (sde - mn) / fabsf(mx - mn);
        conf_s[h]  = conf;
        bool valid = (sde <= 10.0f);
        bool sup   = false;
        if (valid) {
            for (int g = 0; g < HH; ++g) {
                if (g == h) continue;
                float c = nx_s[h] * nx_s[g] + ny_s[h] * ny_s[g] + nz_s[h] * nz_s[g];
                c = fminf(1.0f, fmaxf(-1.0f, c));
                float ang = acosf(c) * 57.29577951308232f;
                bool close = (ang < 30.0f) || (180.0f - ang < 30.0f);
                if (close && (sde_s[g] <= 10.0f) && (sde >= sde_s[g])) sup = true;
            }
        }
        keep_s[h] = (valid && !sup) ? 1 : 0;
    }
    __syncthreads();

    if (tid < HH) {
        int h = tid;
        // stable descending rank on key = keep ? conf : -inf (jnp.argsort(-key))
        float keyh = keep_s[h] ? conf_s[h] : -INFINITY;
        int pos = 0;
        for (int g = 0; g < HH; ++g) {
            float keyg = keep_s[g] ? conf_s[g] : -INFINITY;
            if (keyg > keyh || (keyg == keyh && g < h)) ++pos;
        }
        float nx = nx_s[h], ny = ny_s[h], nz = nz_s[h];
        float t  = nx * cmx + ny * cmy + nz * cmz + d_s[h];
        float px = cmx - t * nx, py = cmy - t * ny, pz = cmz - t * nz;

        float* o = out + (size_t)(b * HH + pos) * 8;
        if (keep_s[h]) {
            o[0] = nx; o[1] = ny; o[2] = nz;
            o[3] = px; o[4] = py; o[5] = pz;
            o[6] = conf_s[h];
            o[7] = sde_s[h];
        } else {
            for (int c = 0; c < 8; ++c) o[c] = 0.0f;
        }
    }
}

extern "C" void kernel_launch(void* const* d_in, const int* in_sizes, int n_in,
                              void* d_out, int out_size, void* d_ws, size_t ws_size,
                              hipStream_t stream) {
    const float* y_pred = (const float*)d_in[0];   // (8,16,4) f32
    const float* sp     = (const float*)d_in[1];   // (8,1024,3) f32
    float* out          = (float*)d_out;           // (8,16,8) f32
    float* ws           = (float*)d_ws;            // 256 floats of block sums

    chamfer_kernel<<<dim3(BB * HH * 2), dim3(TBC), 0, stream>>>(y_pred, sp, ws);
    finalize_kernel<<<dim3(BB), dim3(TB), 0, stream>>>(ws, y_pred, sp, out);
}